// Round 3
// baseline (19962.349 us; speedup 1.0000x reference)
//
#include <hip/hip_runtime.h>
#include <cmath>

#define HID 1024
#define NB  128   // batch
#define NT  512   // seq len
#define NV  128   // vocab

using u16 = unsigned short;
using u32 = unsigned int;

static __device__ __forceinline__ float bf2f(u16 u) {
  union { u32 i; float f; } v; v.i = ((u32)u) << 16; return v.f;
}
static __device__ __forceinline__ u16 f2bf(float f) {
  union { u32 i; float f; } v; v.f = f;
  u32 r = v.i + 0x7FFFu + ((v.i >> 16) & 1u);   // round-to-nearest-even
  return (u16)(r >> 16);
}

// ---------------------------------------------------------------------------
// RNN step: h_t = tanh(Wxh[x_t] + h_{t-1} @ Whh + bh).
// Recurrence stays f32 via ping-pong hprev_g/hcur_g (no bf16 accumulation);
// a bf16 snapshot is archived to Hs for attention/FC.
// grid (8 jt, 32 bt), block 256 = 4 waves; wave w owns batch bt*4+w;
// lane covers j = jt*128 + lane*2 (float2 Whh row slice -> coalesced).
// ---------------------------------------------------------------------------
__global__ __launch_bounds__(256) void rnn_step(
    const int* __restrict__ x, const float* __restrict__ Wxh,
    const float* __restrict__ Whh, const float* __restrict__ bh,
    const float* __restrict__ hprev_g, float* __restrict__ hcur_g,
    u16* __restrict__ Hs, int t)
{
  const int jt   = blockIdx.x;
  const int bt   = blockIdx.y;
  const int w    = threadIdx.x >> 6;
  const int lane = threadIdx.x & 63;
  const int b    = bt * 4 + w;
  const int j    = jt * 128 + lane * 2;

  __shared__ float hprev[4][HID];
  if (t > 0) {
    for (int i = threadIdx.x; i < 4 * HID; i += 256) {
      int bb = i >> 10, kk = i & (HID - 1);
      hprev[bb][kk] = hprev_g[(bt * 4 + bb) * HID + kk];
    }
  }
  __syncthreads();

  const int xt = x[b * NT + t];
  float acc0 = Wxh[xt * HID + j]     + bh[j];
  float acc1 = Wxh[xt * HID + j + 1] + bh[j + 1];

  if (t > 0) {
    const float* __restrict__ hp = hprev[w];
    const float* __restrict__ wp = Whh + j;
    #pragma unroll 16
    for (int k = 0; k < HID; ++k) {
      float  hk = hp[k];
      float2 wv = *reinterpret_cast<const float2*>(wp + (size_t)k * HID);
      acc0 = fmaf(hk, wv.x, acc0);
      acc1 = fmaf(hk, wv.y, acc1);
    }
  }
  float h0 = tanhf(acc0), h1 = tanhf(acc1);
  hcur_g[b * HID + j]     = h0;
  hcur_g[b * HID + j + 1] = h1;
  u32 pk = ((u32)f2bf(h1) << 16) | (u32)f2bf(h0);
  *reinterpret_cast<u32*>(Hs + ((size_t)b * NT + t) * HID + j) = pk;
}

// ---------------------------------------------------------------------------
// gemm_go: per row r=(b,t):
//   half 0: out_pre[r][v] = fc_b[v] + Hs[r] . fc_w[v][0:1024]   -> d_out (f32)
//   half 1: G[r][v]       =           Hs[r] . fc_w[v][1024:2048] -> ws (bf16)
// block 256: v2 = tid&63 covers v2, v2+64; rg = tid>>6 covers 4 rows.
// fc_w chunk staged transposed in LDS [64 k][129 pad].
// ---------------------------------------------------------------------------
__global__ __launch_bounds__(256) void gemm_go(
    const u16* __restrict__ Hs, const float* __restrict__ fcw,
    const float* __restrict__ fcb, float* __restrict__ outpre,
    u16* __restrict__ G)
{
  const int row0 = blockIdx.x * 16;
  const int v2   = threadIdx.x & 63;
  const int rg   = threadIdx.x >> 6;
  __shared__ float Wc[64][129];

  for (int half = 0; half < 2; ++half) {
    float acc[4][2] = {};
    for (int kc = 0; kc < 16; ++kc) {
      __syncthreads();
      for (int jj = 0; jj < 32; ++jj) {
        int idx = threadIdx.x + jj * 256;   // 0..8191
        int k = idx & 63, v = idx >> 6;
        Wc[k][v] = fcw[(size_t)v * 2048 + half * 1024 + kc * 64 + k];
      }
      __syncthreads();
      #pragma unroll
      for (int r = 0; r < 4; ++r) {
        const u16* arow = Hs + (size_t)(row0 + rg * 4 + r) * HID + kc * 64;
        #pragma unroll
        for (int k8 = 0; k8 < 8; ++k8) {
          uint4 u = *reinterpret_cast<const uint4*>(arow + k8 * 8);
          u32 uu[4] = {u.x, u.y, u.z, u.w};
          #pragma unroll
          for (int p = 0; p < 4; ++p) {
            int k = k8 * 8 + p * 2;
            float a0 = bf2f((u16)(uu[p] & 0xffffu));
            float a1 = bf2f((u16)(uu[p] >> 16));
            acc[r][0] = fmaf(a0, Wc[k][v2],          acc[r][0]);
            acc[r][1] = fmaf(a0, Wc[k][v2 + 64],     acc[r][1]);
            acc[r][0] = fmaf(a1, Wc[k + 1][v2],      acc[r][0]);
            acc[r][1] = fmaf(a1, Wc[k + 1][v2 + 64], acc[r][1]);
          }
        }
      }
    }
    if (half == 0) {
      float b0 = fcb[v2], b1 = fcb[v2 + 64];
      #pragma unroll
      for (int r = 0; r < 4; ++r) {
        size_t orow = (size_t)(row0 + rg * 4 + r) * NV;
        outpre[orow + v2]      = acc[r][0] + b0;
        outpre[orow + v2 + 64] = acc[r][1] + b1;
      }
    } else {
      #pragma unroll
      for (int r = 0; r < 4; ++r) {
        size_t orow = (size_t)(row0 + rg * 4 + r) * NV;
        G[orow + v2]      = f2bf(acc[r][0]);
        G[orow + v2 + 64] = f2bf(acc[r][1]);
      }
    }
  }
}

// ---------------------------------------------------------------------------
// flash_attn: one wave per (b, 4 query rows). Online softmax over s,
// PV accumulated in the pre-projected 128-dim G space:
//   out[b,t,v] += (sum_s e_s * G[b,s,v]) / (sum_s e_s)
// k partition per lane: k = i*128 + lane*2 (u32 loads, 256 B/wave).
// Output columns per lane: v = 2*lane, 2*lane+1 (float2 RMW).
// ---------------------------------------------------------------------------
__global__ __launch_bounds__(64) void flash_attn(
    const u16* __restrict__ Hs, const u16* __restrict__ G,
    float* __restrict__ out)
{
  const int blk  = blockIdx.x;        // 128 batches * 128 row-quads
  const int b    = blk >> 7;
  const int t0   = (blk & 127) * 4;
  const int lane = threadIdx.x;
  const u16* __restrict__ Hb = Hs + (size_t)b * NT * HID;
  const u16* __restrict__ Gb = G  + (size_t)b * NT * NV;

  float q[4][16];
  #pragma unroll
  for (int r = 0; r < 4; ++r) {
    const u16* Hq = Hb + (size_t)(t0 + r) * HID;
    #pragma unroll
    for (int i = 0; i < 8; ++i) {
      u32 u = *reinterpret_cast<const u32*>(Hq + i * 128 + lane * 2);
      q[r][2 * i]     = bf2f((u16)(u & 0xffffu));
      q[r][2 * i + 1] = bf2f((u16)(u >> 16));
    }
  }

  float m0 = -INFINITY, m1 = -INFINITY, m2 = -INFINITY, m3 = -INFINITY;
  float l0 = 0.f, l1 = 0.f, l2 = 0.f, l3 = 0.f;
  float a00 = 0.f, a01 = 0.f, a10 = 0.f, a11 = 0.f;
  float a20 = 0.f, a21 = 0.f, a30 = 0.f, a31 = 0.f;

  for (int s = 0; s < NT; ++s) {
    const u16* vrow = Hb + (size_t)s * HID;
    float p0 = 0.f, p1 = 0.f, p2 = 0.f, p3 = 0.f;
    #pragma unroll
    for (int i = 0; i < 8; ++i) {
      u32 u = *reinterpret_cast<const u32*>(vrow + i * 128 + lane * 2);
      float v0 = bf2f((u16)(u & 0xffffu));
      float v1 = bf2f((u16)(u >> 16));
      p0 = fmaf(q[0][2 * i], v0, p0); p0 = fmaf(q[0][2 * i + 1], v1, p0);
      p1 = fmaf(q[1][2 * i], v0, p1); p1 = fmaf(q[1][2 * i + 1], v1, p1);
      p2 = fmaf(q[2][2 * i], v0, p2); p2 = fmaf(q[2][2 * i + 1], v1, p2);
      p3 = fmaf(q[3][2 * i], v0, p3); p3 = fmaf(q[3][2 * i + 1], v1, p3);
    }
    #pragma unroll
    for (int off = 32; off >= 1; off >>= 1) {
      p0 += __shfl_xor(p0, off);
      p1 += __shfl_xor(p1, off);
      p2 += __shfl_xor(p2, off);
      p3 += __shfl_xor(p3, off);
    }
    u32 g = *reinterpret_cast<const u32*>(Gb + s * NV + lane * 2);
    float ga  = bf2f((u16)(g & 0xffffu));
    float gb2 = bf2f((u16)(g >> 16));

    { float mn = fmaxf(m0, p0); float sc = __expf(m0 - mn); float e = __expf(p0 - mn);
      l0 = l0 * sc + e; m0 = mn; a00 = fmaf(e, ga, a00 * sc); a01 = fmaf(e, gb2, a01 * sc); }
    { float mn = fmaxf(m1, p1); float sc = __expf(m1 - mn); float e = __expf(p1 - mn);
      l1 = l1 * sc + e; m1 = mn; a10 = fmaf(e, ga, a10 * sc); a11 = fmaf(e, gb2, a11 * sc); }
    { float mn = fmaxf(m2, p2); float sc = __expf(m2 - mn); float e = __expf(p2 - mn);
      l2 = l2 * sc + e; m2 = mn; a20 = fmaf(e, ga, a20 * sc); a21 = fmaf(e, gb2, a21 * sc); }
    { float mn = fmaxf(m3, p3); float sc = __expf(m3 - mn); float e = __expf(p3 - mn);
      l3 = l3 * sc + e; m3 = mn; a30 = fmaf(e, ga, a30 * sc); a31 = fmaf(e, gb2, a31 * sc); }
  }

  #pragma unroll
  for (int r = 0; r < 4; ++r) {
    float ar0 = (r == 0) ? a00 : (r == 1) ? a10 : (r == 2) ? a20 : a30;
    float ar1 = (r == 0) ? a01 : (r == 1) ? a11 : (r == 2) ? a21 : a31;
    float lr  = (r == 0) ? l0  : (r == 1) ? l1  : (r == 2) ? l2  : l3;
    float inv = 1.f / lr;
    float2* po = reinterpret_cast<float2*>(out + ((size_t)b * NT + t0 + r) * NV) + lane;
    float2 o = *po;
    o.x += ar0 * inv;
    o.y += ar1 * inv;
    *po = o;
  }
}

// ---------------------------------------------------------------------------
// Workspace layout (ws usage ~145 MiB):
//   Hs  bf16 [128][512][1024]  134,217,728 B
//   G   bf16 [128][512][128]    16,777,216 B
//   hA  f32  [128][1024]           524,288 B
//   hB  f32  [128][1024]           524,288 B
// ---------------------------------------------------------------------------
extern "C" void kernel_launch(void* const* d_in, const int* in_sizes, int n_in,
                              void* d_out, int out_size, void* d_ws, size_t ws_size,
                              hipStream_t stream)
{
  const int*   x   = (const int*)  d_in[0];
  const float* Wxh = (const float*)d_in[1];
  const float* Whh = (const float*)d_in[2];
  const float* bh  = (const float*)d_in[3];
  const float* fcw = (const float*)d_in[4];
  const float* fcb = (const float*)d_in[5];
  float* out = (float*)d_out;

  u16* Hs = (u16*)d_ws;
  u16* G  = Hs + (size_t)NB * NT * HID;
  float* hbuf = (float*)(G + (size_t)NB * NT * NV);
  float* hA = hbuf;
  float* hB = hbuf + NB * HID;

  // 1) sequential RNN scan; f32 recurrence in ping-pong buffers, bf16 archive
  for (int t = 0; t < NT; ++t) {
    const float* hp = (t & 1) ? hA : hB;   // previous h (unused at t=0)
    float*       hc = (t & 1) ? hB : hA;   // current h
    rnn_step<<<dim3(8, 32), 256, 0, stream>>>(x, Wxh, Whh, bh, hp, hc, Hs, t);
  }

  // 2) out_pre = Hs @ W1^T + fc_b (d_out, f32);  G = Hs @ W2^T (ws, bf16)
  gemm_go<<<dim3((NB * NT) / 16), 256, 0, stream>>>(Hs, fcw, fcb, out, G);

  // 3) flash attention in projected space: out += softmax(Hs Hs^T) @ G
  flash_attn<<<dim3(NB * (NT / 4)), 64, 0, stream>>>(Hs, G, out);
}

// Round 4
// 9851.723 us; speedup vs baseline: 2.0263x; 2.0263x over previous
//
#include <hip/hip_runtime.h>
#include <cmath>

#define HID 1024
#define NB  128   // batch
#define NT  512   // seq len
#define NV  128   // vocab
#define NBLK 256  // persistent RNN blocks (8 batch-groups x 32 col-groups)

using u16 = unsigned short;
using u32 = unsigned int;

typedef __attribute__((ext_vector_type(8))) short s16x8;
typedef __attribute__((ext_vector_type(4))) float f32x4;

static __device__ __forceinline__ float bf2f(u16 u) {
  union { u32 i; float f; } v; v.i = ((u32)u) << 16; return v.f;
}
static __device__ __forceinline__ u16 f2bf(float f) {
  union { u32 i; float f; } v; v.f = f;
  u32 r = v.i + 0x7FFFu + ((v.i >> 16) & 1u);   // round-to-nearest-even
  return (u16)(r >> 16);
}

// ---------------------------------------------------------------------------
// Persistent RNN: ALL 512 steps in one kernel. Whh slice lives in LDS (bf16,
// transposed, XOR-swizzled) -> immune to the per-step L2 invalidates that made
// the 512-launch version re-stream Whh from L3 every step (~35 us/step).
// Decomposition: block = (bg, cg): 16 batches x 32 output cols. Step:
//   S[16x32] = h_prev[16x1024](bf16, global dbuf) @ WtLDS  via mfma 16x16x32
//   h = tanhf(S + Wxh[x_t] + bh)  (f32 epilogue)
// Exchange h across the 32 col-blocks of a bg via global dbuf + manual
// agent-scope barrier (atomicAdd release / spin acquire), 1 per step.
// Numerics: recurrence accumulate f32; only Whh and stored h are bf16 —
// contraction (|J|~0.3) keeps steady-state error ~2e-5 on h.
// ---------------------------------------------------------------------------
__global__ __launch_bounds__(128, 1) void rnn_persist(
    const int* __restrict__ x, const float* __restrict__ Wxh,
    const float* __restrict__ Whh, const float* __restrict__ bh,
    u16* __restrict__ Hs, u16* __restrict__ hbuf, u32* __restrict__ ctr)
{
  const int blk  = blockIdx.x;
  const int bg   = blk >> 5;        // 0..7   -> batches bg*16 .. +16
  const int cg   = blk & 31;        // 0..31  -> cols cg*32 .. +32
  const int tid  = threadIdx.x;     // 0..127 (2 waves)
  const int wave = tid >> 6;
  const int lane = tid & 63;
  const int b0   = bg * 16;
  const int c0   = cg * 32;

  __shared__ u16  Wt[32 * 1024];    // [col][k] bf16, byte-XOR-swizzled
  __shared__ float xe[16][33];      // per-step Wxh[x_t]+bh slice (pad 33)

  // ---- stage Wt (transpose Whh[k][c0+col] -> Wt[col][k], bf16, swizzle) ----
  for (int it = 0; it < 128; ++it) {
    int idx = tid + it * 128;       // 0..16383
    int col = idx & 31;
    int k   = (idx >> 5) * 2;       // k pair
    float w0 = Whh[(size_t)k * HID + c0 + col];
    float w1 = Whh[(size_t)(k + 1) * HID + c0 + col];
    u32 pk = ((u32)f2bf(w1) << 16) | (u32)f2bf(w0);
    u32 byteo = ((u32)col * 2048 + (u32)k * 2) ^ ((u32)(col & 7) << 4);
    *reinterpret_cast<u32*>(reinterpret_cast<char*>(Wt) + byteo) = pk;
  }
  __syncthreads();

  // MFMA fragment geometry (16x16x32 bf16):
  //   A: row = lane&15 (batch m), k-slice = (lane>>4)*8
  //   B: col = lane&15 (out col n), k-slice = (lane>>4)*8
  //   C: n = lane&15, m = (lane>>4)*4 + reg
  const int frow = lane & 15;
  const int koff = (lane >> 4) * 8;
  const int col  = wave * 16 + (lane & 15);
  const u32 swz   = (u32)(col & 7) << 4;
  const u32 bbase = (u32)col * 2048 + (u32)koff * 2;
  const char* wtb = reinterpret_cast<const char*>(Wt);

  for (int t = 0; t < NT; ++t) {
    // ---- gather xe = Wxh[x_t] + bh for this (bg, cg) slice ----
    {
      int idx = tid * 4;            // 512 f32 total, 4 per thread
      int b = idx >> 5;
      int c = idx & 31;
      int xt = x[(size_t)(b0 + b) * NT + t];
      float4 wv = *reinterpret_cast<const float4*>(Wxh + (size_t)xt * HID + c0 + c);
      float4 bv = *reinterpret_cast<const float4*>(bh + c0 + c);
      xe[b][c]     = wv.x + bv.x;
      xe[b][c + 1] = wv.y + bv.y;
      xe[b][c + 2] = wv.z + bv.z;
      xe[b][c + 3] = wv.w + bv.w;
    }
    __syncthreads();

    // ---- S = h_prev @ Wslice via MFMA (K = 1024 = 32 chunks) ----
    f32x4 acc = {0.f, 0.f, 0.f, 0.f};
    if (t > 0) {
      const u16* hprev = hbuf + (size_t)(t & 1) * NB * HID;
      const u16* ap = hprev + (size_t)(b0 + frow) * HID + koff;
      #pragma unroll 8
      for (int kc = 0; kc < 32; ++kc) {
        s16x8 af = *reinterpret_cast<const s16x8*>(ap + kc * 32);
        s16x8 bf = *reinterpret_cast<const s16x8*>(wtb + ((bbase + (u32)kc * 64) ^ swz));
        acc = __builtin_amdgcn_mfma_f32_16x16x32_bf16(af, bf, acc, 0, 0, 0);
      }
    }

    // ---- epilogue: tanh, publish h_t (dbuf) + archive to Hs ----
    u16* hnext = hbuf + (size_t)((t + 1) & 1) * NB * HID;
    #pragma unroll
    for (int r = 0; r < 4; ++r) {
      int m = (lane >> 4) * 4 + r;
      float h = tanhf(acc[r] + xe[m][col]);
      u16 hb = f2bf(h);
      hnext[(size_t)(b0 + m) * HID + c0 + col] = hb;
      Hs[((size_t)(b0 + m) * NT + t) * HID + c0 + col] = hb;
    }

    // ---- device-scope barrier: release h_t, wait for all 256 blocks ----
    __syncthreads();   // drains this block's stores (vmcnt0 before s_barrier)
    if (tid == 0) {
      __hip_atomic_fetch_add(ctr, 1u, __ATOMIC_RELEASE, __HIP_MEMORY_SCOPE_AGENT);
      const u32 target = (u32)NBLK * (u32)(t + 1);
      while (__hip_atomic_load(ctr, __ATOMIC_ACQUIRE, __HIP_MEMORY_SCOPE_AGENT) < target) {
        __builtin_amdgcn_s_sleep(4);
      }
    }
    __syncthreads();
  }
}

// ---------------------------------------------------------------------------
// gemm_go: per row r=(b,t):
//   half 0: out_pre[r][v] = fc_b[v] + Hs[r] . fc_w[v][0:1024]   -> d_out (f32)
//   half 1: G[r][v]       =           Hs[r] . fc_w[v][1024:2048] -> ws (bf16)
// ---------------------------------------------------------------------------
__global__ __launch_bounds__(256) void gemm_go(
    const u16* __restrict__ Hs, const float* __restrict__ fcw,
    const float* __restrict__ fcb, float* __restrict__ outpre,
    u16* __restrict__ G)
{
  const int row0 = blockIdx.x * 16;
  const int v2   = threadIdx.x & 63;
  const int rg   = threadIdx.x >> 6;
  __shared__ float Wc[64][129];

  for (int half = 0; half < 2; ++half) {
    float acc[4][2] = {};
    for (int kc = 0; kc < 16; ++kc) {
      __syncthreads();
      for (int jj = 0; jj < 32; ++jj) {
        int idx = threadIdx.x + jj * 256;   // 0..8191
        int k = idx & 63, v = idx >> 6;
        Wc[k][v] = fcw[(size_t)v * 2048 + half * 1024 + kc * 64 + k];
      }
      __syncthreads();
      #pragma unroll
      for (int r = 0; r < 4; ++r) {
        const u16* arow = Hs + (size_t)(row0 + rg * 4 + r) * HID + kc * 64;
        #pragma unroll
        for (int k8 = 0; k8 < 8; ++k8) {
          uint4 u = *reinterpret_cast<const uint4*>(arow + k8 * 8);
          u32 uu[4] = {u.x, u.y, u.z, u.w};
          #pragma unroll
          for (int p = 0; p < 4; ++p) {
            int k = k8 * 8 + p * 2;
            float a0 = bf2f((u16)(uu[p] & 0xffffu));
            float a1 = bf2f((u16)(uu[p] >> 16));
            acc[r][0] = fmaf(a0, Wc[k][v2],          acc[r][0]);
            acc[r][1] = fmaf(a0, Wc[k][v2 + 64],     acc[r][1]);
            acc[r][0] = fmaf(a1, Wc[k + 1][v2],      acc[r][0]);
            acc[r][1] = fmaf(a1, Wc[k + 1][v2 + 64], acc[r][1]);
          }
        }
      }
    }
    if (half == 0) {
      float b0 = fcb[v2], b1 = fcb[v2 + 64];
      #pragma unroll
      for (int r = 0; r < 4; ++r) {
        size_t orow = (size_t)(row0 + rg * 4 + r) * NV;
        outpre[orow + v2]      = acc[r][0] + b0;
        outpre[orow + v2 + 64] = acc[r][1] + b1;
      }
    } else {
      #pragma unroll
      for (int r = 0; r < 4; ++r) {
        size_t orow = (size_t)(row0 + rg * 4 + r) * NV;
        G[orow + v2]      = f2bf(acc[r][0]);
        G[orow + v2 + 64] = f2bf(acc[r][1]);
      }
    }
  }
}

// ---------------------------------------------------------------------------
// flash_attn: one wave per (b, 4 query rows). Online softmax over s,
// PV accumulated in the pre-projected 128-dim G space.
// ---------------------------------------------------------------------------
__global__ __launch_bounds__(64) void flash_attn(
    const u16* __restrict__ Hs, const u16* __restrict__ G,
    float* __restrict__ out)
{
  const int blk  = blockIdx.x;        // 128 batches * 128 row-quads
  const int b    = blk >> 7;
  const int t0   = (blk & 127) * 4;
  const int lane = threadIdx.x;
  const u16* __restrict__ Hb = Hs + (size_t)b * NT * HID;
  const u16* __restrict__ Gb = G  + (size_t)b * NT * NV;

  float q[4][16];
  #pragma unroll
  for (int r = 0; r < 4; ++r) {
    const u16* Hq = Hb + (size_t)(t0 + r) * HID;
    #pragma unroll
    for (int i = 0; i < 8; ++i) {
      u32 u = *reinterpret_cast<const u32*>(Hq + i * 128 + lane * 2);
      q[r][2 * i]     = bf2f((u16)(u & 0xffffu));
      q[r][2 * i + 1] = bf2f((u16)(u >> 16));
    }
  }

  float m0 = -INFINITY, m1 = -INFINITY, m2 = -INFINITY, m3 = -INFINITY;
  float l0 = 0.f, l1 = 0.f, l2 = 0.f, l3 = 0.f;
  float a00 = 0.f, a01 = 0.f, a10 = 0.f, a11 = 0.f;
  float a20 = 0.f, a21 = 0.f, a30 = 0.f, a31 = 0.f;

  for (int s = 0; s < NT; ++s) {
    const u16* vrow = Hb + (size_t)s * HID;
    float p0 = 0.f, p1 = 0.f, p2 = 0.f, p3 = 0.f;
    #pragma unroll
    for (int i = 0; i < 8; ++i) {
      u32 u = *reinterpret_cast<const u32*>(vrow + i * 128 + lane * 2);
      float v0 = bf2f((u16)(u & 0xffffu));
      float v1 = bf2f((u16)(u >> 16));
      p0 = fmaf(q[0][2 * i], v0, p0); p0 = fmaf(q[0][2 * i + 1], v1, p0);
      p1 = fmaf(q[1][2 * i], v0, p1); p1 = fmaf(q[1][2 * i + 1], v1, p1);
      p2 = fmaf(q[2][2 * i], v0, p2); p2 = fmaf(q[2][2 * i + 1], v1, p2);
      p3 = fmaf(q[3][2 * i], v0, p3); p3 = fmaf(q[3][2 * i + 1], v1, p3);
    }
    #pragma unroll
    for (int off = 32; off >= 1; off >>= 1) {
      p0 += __shfl_xor(p0, off);
      p1 += __shfl_xor(p1, off);
      p2 += __shfl_xor(p2, off);
      p3 += __shfl_xor(p3, off);
    }
    u32 g = *reinterpret_cast<const u32*>(Gb + s * NV + lane * 2);
    float ga  = bf2f((u16)(g & 0xffffu));
    float gb2 = bf2f((u16)(g >> 16));

    { float mn = fmaxf(m0, p0); float sc = __expf(m0 - mn); float e = __expf(p0 - mn);
      l0 = l0 * sc + e; m0 = mn; a00 = fmaf(e, ga, a00 * sc); a01 = fmaf(e, gb2, a01 * sc); }
    { float mn = fmaxf(m1, p1); float sc = __expf(m1 - mn); float e = __expf(p1 - mn);
      l1 = l1 * sc + e; m1 = mn; a10 = fmaf(e, ga, a10 * sc); a11 = fmaf(e, gb2, a11 * sc); }
    { float mn = fmaxf(m2, p2); float sc = __expf(m2 - mn); float e = __expf(p2 - mn);
      l2 = l2 * sc + e; m2 = mn; a20 = fmaf(e, ga, a20 * sc); a21 = fmaf(e, gb2, a21 * sc); }
    { float mn = fmaxf(m3, p3); float sc = __expf(m3 - mn); float e = __expf(p3 - mn);
      l3 = l3 * sc + e; m3 = mn; a30 = fmaf(e, ga, a30 * sc); a31 = fmaf(e, gb2, a31 * sc); }
  }

  #pragma unroll
  for (int r = 0; r < 4; ++r) {
    float ar0 = (r == 0) ? a00 : (r == 1) ? a10 : (r == 2) ? a20 : a30;
    float ar1 = (r == 0) ? a01 : (r == 1) ? a11 : (r == 2) ? a21 : a31;
    float lr  = (r == 0) ? l0  : (r == 1) ? l1  : (r == 2) ? l2  : l3;
    float inv = 1.f / lr;
    float2* po = reinterpret_cast<float2*>(out + ((size_t)b * NT + t0 + r) * NV) + lane;
    float2 o = *po;
    o.x += ar0 * inv;
    o.y += ar1 * inv;
    *po = o;
  }
}

// ---------------------------------------------------------------------------
// Workspace layout (~144.6 MiB):
//   Hs   bf16 [128][512][1024]  134,217,728 B
//   G    bf16 [128][512][128]    16,777,216 B
//   hbuf bf16 [2][128][1024]        524,288 B
//   ctr  u32                            256 B
// ---------------------------------------------------------------------------
extern "C" void kernel_launch(void* const* d_in, const int* in_sizes, int n_in,
                              void* d_out, int out_size, void* d_ws, size_t ws_size,
                              hipStream_t stream)
{
  const int*   x   = (const int*)  d_in[0];
  const float* Wxh = (const float*)d_in[1];
  const float* Whh = (const float*)d_in[2];
  const float* bh  = (const float*)d_in[3];
  const float* fcw = (const float*)d_in[4];
  const float* fcb = (const float*)d_in[5];
  float* out = (float*)d_out;

  u16* Hs   = (u16*)d_ws;
  u16* G    = Hs + (size_t)NB * NT * HID;
  u16* hbuf = G + (size_t)NB * NT * NV;
  u32* ctr  = (u32*)(hbuf + 2 * (size_t)NB * HID);

  // zero the barrier counter (ws is re-poisoned 0xAA before every launch)
  hipMemsetAsync(ctr, 0, 4, stream);

  // 1) persistent RNN: all 512 steps, one kernel
  rnn_persist<<<NBLK, 128, 0, stream>>>(x, Wxh, Whh, bh, Hs, hbuf, ctr);

  // 2) out_pre = Hs @ W1^T + fc_b (d_out, f32);  G = Hs @ W2^T (ws, bf16)
  gemm_go<<<dim3((NB * NT) / 16), 256, 0, stream>>>(Hs, fcw, fcb, out, G);

  // 3) flash attention in projected space: out += softmax(Hs Hs^T) @ G
  flash_attn<<<dim3(NB * (NT / 4)), 64, 0, stream>>>(Hs, G, out);
}